// Round 9
// baseline (311.714 us; speedup 1.0000x reference)
//
#include <hip/hip_runtime.h>

#define FD 128      // feature dim (both layers)
#define BSH 7       // log2(nodes per bucket) = 128 nodes/bucket
#define BPAD 16     // cursor padding (ints) -> one per 64B line
#define CH 4096     // edges per partition block
#define CHT 16      // edges per thread (CH / 256)
// packed pair: (local_dst << 17) | src   -- requires N <= 131072

typedef __attribute__((ext_vector_type(8))) short bf16x8;
typedef __attribute__((ext_vector_type(4))) float f32x4;
typedef __attribute__((ext_vector_type(2))) unsigned int u32x2;  // native vec for nontemporal builtins

__device__ inline unsigned bfr(float f) {   // fp32 -> bf16 bits, round-nearest-even
    unsigned u = __float_as_uint(f);
    return (u + 0x7FFF + ((u >> 16) & 1)) >> 16;
}
__device__ inline float uplo(unsigned p) { return __uint_as_float(p << 16); }
__device__ inline float uphi(unsigned p) { return __uint_as_float(p & 0xFFFF0000u); }

// ---------------- CSR build ----------------

__global__ __launch_bounds__(256) void hist_kernel(
        const int* __restrict__ dst, int* __restrict__ bhist, int E, int K) {
    __shared__ int lh[512];
    for (int i = threadIdx.x; i < K; i += 256) lh[i] = 0;
    __syncthreads();
    for (int e = blockIdx.x * 256 + threadIdx.x; e < E; e += gridDim.x * 256)
        atomicAdd(&lh[dst[e] >> BSH], 1);
    __syncthreads();
    for (int i = threadIdx.x; i < K; i += 256)
        if (lh[i]) atomicAdd(&bhist[i], lh[i]);
}

__global__ __launch_bounds__(512) void bscan_kernel(
        const int* __restrict__ bhist, int* __restrict__ bbase, int* __restrict__ bcur,
        int* __restrict__ rp, int K, int E, int N) {
    __shared__ int sm[512];
    int t = threadIdx.x;
    int v = (t < K) ? bhist[t] : 0;
    sm[t] = v;
    __syncthreads();
    for (int off = 1; off < 512; off <<= 1) {
        int add = (t >= off) ? sm[t - off] : 0;
        __syncthreads();
        sm[t] += add;
        __syncthreads();
    }
    if (t < K) { bbase[t] = sm[t] - v; bcur[t * BPAD] = sm[t] - v; }
    if (t == 0) { bbase[K] = E; rp[N] = E; }
}

// Block-local multi-split partition (R6: ~1-2 writebacks per pairs-line,
// independent of block->XCD placement).
__global__ __launch_bounds__(256) void partition_kernel(
        const int* __restrict__ src, const int* __restrict__ dst,
        int* __restrict__ bcur, int* __restrict__ pairs, int E) {
    __shared__ int   lcnt[512];
    __shared__ int   lstart[512];
    __shared__ int   ldelta[512];
    __shared__ int   sm[256];
    __shared__ int   staged[CH];
    __shared__ short binof[CH];
    int t = threadIdx.x;
    int base = blockIdx.x * CH;
    int n = min(CH, E - base);

    lcnt[t] = 0; lcnt[t + 256] = 0;
    __syncthreads();

    int pk[CHT]; int bn[CHT];
    #pragma unroll
    for (int j = 0; j < CHT; ++j) {
        int i = t + j * 256;
        bn[j] = -1;
        if (i < n) {
            int d = dst[base + i];
            int s = src[base + i];
            bn[j] = d >> BSH;
            pk[j] = ((d & ((1 << BSH) - 1)) << 17) | s;
            atomicAdd(&lcnt[bn[j]], 1);
        }
    }
    __syncthreads();

    int c0 = lcnt[2 * t], c1 = lcnt[2 * t + 1];
    int s2 = c0 + c1;
    sm[t] = s2;
    __syncthreads();
    for (int off = 1; off < 256; off <<= 1) {
        int add = (t >= off) ? sm[t - off] : 0;
        __syncthreads();
        sm[t] += add;
        __syncthreads();
    }
    int ex = sm[t] - s2;
    lstart[2 * t] = ex;     lstart[2 * t + 1] = ex + c0;
    lcnt[2 * t]   = ex;     lcnt[2 * t + 1]   = ex + c0;
    __syncthreads();

    #pragma unroll
    for (int j = 0; j < CHT; ++j) {
        if (bn[j] >= 0) {
            int pos = atomicAdd(&lcnt[bn[j]], 1);
            staged[pos] = pk[j];
            binof[pos] = (short)bn[j];
        }
    }
    __syncthreads();

    #pragma unroll
    for (int k = 0; k < 2; ++k) {
        int b = 2 * t + k;
        int cnt = lcnt[b] - lstart[b];
        if (cnt > 0) {
            int g = atomicAdd(&bcur[b * BPAD], cnt);
            ldelta[b] = g - lstart[b];
        }
    }
    __syncthreads();

    for (int i = t; i < n; i += 256)
        pairs[ldelta[binof[i]] + i] = staged[i];
}

__global__ __launch_bounds__(256) void build_kernel(
        const int* __restrict__ pairs, const int* __restrict__ bbase,
        int* __restrict__ rp, float* __restrict__ dis, int* __restrict__ col, int N) {
    __shared__ int lcnt[1 << BSH];
    __shared__ int lsum[1 << BSH];
    __shared__ int lbase[1 << BSH];
    int b = blockIdx.x;
    int t = threadIdx.x;
    int nbase = b << BSH;
    int nn = min(1 << BSH, N - nbase);
    int beg = bbase[b], end = bbase[b + 1];
    if (t < 128) lcnt[t] = 0;
    __syncthreads();
    for (int e = beg + t; e < end; e += 256)
        atomicAdd(&lcnt[pairs[e] >> 17], 1);
    __syncthreads();
    if (t < 128) lsum[t] = lcnt[t];
    __syncthreads();
    for (int off = 1; off < 128; off <<= 1) {
        int add = (t < 128 && t >= off) ? lsum[t - off] : 0;
        __syncthreads();
        if (t < 128) lsum[t] += add;
        __syncthreads();
    }
    if (t < 128) {
        int excl = beg + lsum[t] - lcnt[t];
        lbase[t] = excl;
        if (t < nn) {
            rp[nbase + t] = excl;
            dis[nbase + t] = rsqrtf((float)(lcnt[t] + 1));  // deg incl. self-loop
        }
    }
    __syncthreads();
    if (t < 128) lcnt[t] = lbase[t];
    __syncthreads();
    for (int e = beg + t; e < end; e += 256) {
        int p = pairs[e];
        int pos = atomicAdd(&lcnt[p >> 17], 1);
        col[pos] = p & 0x1FFFF;
    }
}

// ---------------- precision prep ----------------

// W[k][n] fp32 -> WT[n][k] bf16, both weights in one launch (gridDim.x = 2*FD)
__global__ void wt_kernel(const float* __restrict__ W1, unsigned short* __restrict__ W1T,
                          const float* __restrict__ W2, unsigned short* __restrict__ W2T) {
    int k = blockIdx.x & (FD - 1);
    int n = threadIdx.x;
    if (blockIdx.x < FD) W1T[n * FD + k] = (unsigned short)bfr(W1[k * FD + n]);
    else                 W2T[n * FD + k] = (unsigned short)bfr(W2[k * FD + n]);
}

// ---------------- MFMA bf16 GEMM: C = bf16( dis[row] * (A @ W) ) ----------------
// WT: [128 x 128] bf16, WT[n][k]. Block: 128 rows, full K=N=128 in LDS.
// 4 waves, 32 rows each. Mappings (guide-verified): A[m=lane&15][k=quad*8+j],
// B[k=quad*8+j][n=lane&15], C/D row=quad*4+reg, col=lane&15.
// A32 variant: A is fp32, converted to bf16 during staging (fuses cvt pass).

#define APAD 8
#define ASTR (FD + APAD)

template <bool A32>
__device__ void gemm_body(const void* __restrict__ Ap,
                          const unsigned short* __restrict__ WT,
                          const float* __restrict__ dis,
                          unsigned short* __restrict__ C, int M) {
    __shared__ unsigned short As[128 * ASTR];
    __shared__ unsigned short Bs[128 * ASTR];
    int tid = threadIdx.x;
    int lane = tid & 63;
    int wave = tid >> 6;
    int quad = lane >> 4;
    int l16 = lane & 15;
    int rowBase = blockIdx.x * 128;

    #pragma unroll
    for (int p = 0; p < 8; ++p) {
        int r = p * 16 + (tid >> 4);
        int cq = (tid & 15) * 8;
        int gr = rowBase + r;
        uint4 v = make_uint4(0u, 0u, 0u, 0u);
        if (A32) {
            if (gr < M) {
                const float* a = (const float*)Ap + (size_t)gr * FD + cq;
                float4 f0 = *(const float4*)a;
                float4 f1 = *(const float4*)(a + 4);
                v.x = bfr(f0.x) | (bfr(f0.y) << 16);
                v.y = bfr(f0.z) | (bfr(f0.w) << 16);
                v.z = bfr(f1.x) | (bfr(f1.y) << 16);
                v.w = bfr(f1.z) | (bfr(f1.w) << 16);
            }
        } else {
            if (gr < M) v = *(const uint4*)((const unsigned short*)Ap + (size_t)gr * FD + cq);
        }
        *(uint4*)&As[r * ASTR + cq] = v;
        *(uint4*)&Bs[r * ASTR + cq] = *(const uint4*)&WT[(size_t)r * FD + cq];
    }
    __syncthreads();

    int m0 = wave * 32;
    f32x4 acc[2][8] = {};
    #pragma unroll
    for (int kt = 0; kt < 4; ++kt) {
        int ko = kt * 32 + quad * 8;
        bf16x8 a0 = *(bf16x8*)&As[(m0 + l16) * ASTR + ko];
        bf16x8 a1 = *(bf16x8*)&As[(m0 + 16 + l16) * ASTR + ko];
        #pragma unroll
        for (int n = 0; n < 8; ++n) {
            bf16x8 b = *(bf16x8*)&Bs[(n * 16 + l16) * ASTR + ko];
            acc[0][n] = __builtin_amdgcn_mfma_f32_16x16x32_bf16(a0, b, acc[0][n], 0, 0, 0);
            acc[1][n] = __builtin_amdgcn_mfma_f32_16x16x32_bf16(a1, b, acc[1][n], 0, 0, 0);
        }
    }

    #pragma unroll
    for (int ms = 0; ms < 2; ++ms) {
        #pragma unroll
        for (int r = 0; r < 4; ++r) {
            int grow = rowBase + m0 + ms * 16 + quad * 4 + r;
            if (grow < M) {
                float dv = dis[grow];
                #pragma unroll
                for (int n = 0; n < 8; ++n) {
                    C[(size_t)grow * FD + n * 16 + l16] =
                        (unsigned short)bfr(dv * acc[ms][n][r]);
                }
            }
        }
    }
}

__global__ __launch_bounds__(256) void gemm_mfma_f32(
        const float* __restrict__ A, const unsigned short* __restrict__ WT,
        const float* __restrict__ dis, unsigned short* __restrict__ C, int M) {
    gemm_body<true>(A, WT, dis, C, M);
}

__global__ __launch_bounds__(256) void gemm_mfma_bf16(
        const unsigned short* __restrict__ A, const unsigned short* __restrict__ WT,
        const float* __restrict__ dis, unsigned short* __restrict__ C, int M) {
    gemm_body<false>(A, WT, dis, C, M);
}

// ---------------- CSR aggregation + bias + ReLU ----------------
// h' rows pre-scaled by dis, stored bf16. One node per wave; 32 lanes per row
// (u32x2 = 4 bf16 features per lane), TWO edges per gather instruction
// (low half = edge e, high half = edge e+1) -> 2x bytes in flight per vmem slot.
// Cross-half shfl_xor(32) folds the two partial sums.
// out[v] = relu( dis[v] * ( h'[v] + sum_u h'[u] ) + b )
// obf=1: write packed bf16 (z1, feeds gemm2); obf=0: write fp32 (final out).

__global__ __launch_bounds__(256) void agg_kernel(
        const unsigned* __restrict__ h, const float* __restrict__ dis,
        const int* __restrict__ rp, const int* __restrict__ col,
        const float4* __restrict__ bias, void* __restrict__ out, int N, int obf) {
    int v = blockIdx.x * 4 + threadIdx.y;          // blockDim = (64, 4): wave per node
    v = __builtin_amdgcn_readfirstlane(v);         // wave-uniform -> scalar rp/col loads
    if (v >= N) return;
    int t = threadIdx.x;                           // 0..63
    int tl = t & 31;                               // feature quad: 4tl..4tl+3
    int hh = t >> 5;                               // 0: even edge, 1: odd edge
    float4 acc = make_float4(0.f, 0.f, 0.f, 0.f);
    int e = rp[v];
    int end = rp[v + 1];

    for (; e + 16 <= end; e += 16) {
        int u[8];
        #pragma unroll
        for (int j = 0; j < 8; ++j) {
            int a = col[e + 2 * j];                // wave-uniform (scalar)
            int b = col[e + 2 * j + 1];
            u[j] = hh ? b : a;                     // one cndmask
        }
        #pragma unroll
        for (int j = 0; j < 8; ++j) {
            u32x2 p = __builtin_nontemporal_load((const u32x2*)(h + (size_t)u[j] * 64) + tl);
            acc.x += uplo(p.x); acc.y += uphi(p.x);
            acc.z += uplo(p.y); acc.w += uphi(p.y);
        }
    }
    for (; e + 2 <= end; e += 2) {
        int a = col[e], b = col[e + 1];
        int uu = hh ? b : a;
        u32x2 p = __builtin_nontemporal_load((const u32x2*)(h + (size_t)uu * 64) + tl);
        acc.x += uplo(p.x); acc.y += uphi(p.x);
        acc.z += uplo(p.y); acc.w += uphi(p.y);
    }
    if (e < end) {                                 // odd leftover: low half only
        int a = col[e];
        u32x2 p = __builtin_nontemporal_load((const u32x2*)(h + (size_t)a * 64) + tl);
        if (hh == 0) {
            acc.x += uplo(p.x); acc.y += uphi(p.x);
            acc.z += uplo(p.y); acc.w += uphi(p.y);
        }
    }

    // fold high half into low half
    acc.x += __shfl_xor(acc.x, 32);
    acc.y += __shfl_xor(acc.y, 32);
    acc.z += __shfl_xor(acc.z, 32);
    acc.w += __shfl_xor(acc.w, 32);

    if (hh == 0) {
        u32x2 p = *((const u32x2*)(h + (size_t)v * 64) + tl);   // self term h'[v]
        acc.x += uplo(p.x); acc.y += uphi(p.x);
        acc.z += uplo(p.y); acc.w += uphi(p.y);
        float dv = dis[v];
        float4 bb = bias[tl];
        float4 r;
        r.x = fmaxf(fmaf(dv, acc.x, bb.x), 0.0f);
        r.y = fmaxf(fmaf(dv, acc.y, bb.y), 0.0f);
        r.z = fmaxf(fmaf(dv, acc.z, bb.z), 0.0f);
        r.w = fmaxf(fmaf(dv, acc.w, bb.w), 0.0f);
        if (obf) {
            uint2 o;
            o.x = bfr(r.x) | (bfr(r.y) << 16);
            o.y = bfr(r.z) | (bfr(r.w) << 16);
            ((uint2*)out)[(size_t)v * 32 + tl] = o;
        } else {
            ((float4*)out)[(size_t)v * 32 + tl] = r;
        }
    }
}

// ---------------- launch ----------------

extern "C" void kernel_launch(void* const* d_in, const int* in_sizes, int n_in,
                              void* d_out, int out_size, void* d_ws, size_t ws_size,
                              hipStream_t stream) {
    const float* x  = (const float*)d_in[0];
    const int*   ei = (const int*)d_in[1];   // [2, E] int32
    const float* W1 = (const float*)d_in[2];
    const float* b1 = (const float*)d_in[3];
    const float* W2 = (const float*)d_in[4];
    const float* b2 = (const float*)d_in[5];

    int N = in_sizes[0] / FD;
    int E = in_sizes[1] / 2;
    const int* src = ei;
    const int* dst = ei + E;
    int K = (N + (1 << BSH) - 1) >> BSH;     // buckets (<= 512 assumed)

    char* base = (char*)d_ws;
    size_t off = 0;
    auto align256 = [](size_t v) { return (v + 255) & ~(size_t)255; };
    int*            rp    = (int*)(base + off);            off += align256((size_t)(N + 1) * 4);
    float*          dis   = (float*)(base + off);          off += align256((size_t)N * 4);
    int*            bhist = (int*)(base + off);            off += align256(512 * 4);
    int*            bbase = (int*)(base + off);            off += align256(513 * 4);
    int*            bcur  = (int*)(base + off);            off += align256((size_t)K * BPAD * 4);
    unsigned short* w1t   = (unsigned short*)(base + off); off += align256((size_t)FD * FD * 2);
    unsigned short* w2t   = (unsigned short*)(base + off); off += align256((size_t)FD * FD * 2);
    int*            col   = (int*)(base + off);            off += align256((size_t)E * 4);
    unsigned short* hbuf  = (unsigned short*)(base + off); off += align256((size_t)N * FD * 2);
    unsigned short* z1    = (unsigned short*)(base + off); off += align256((size_t)N * FD * 2);
    int*            pairs = (int*)(base + off);            off += align256((size_t)E * 4);
    (void)ws_size; (void)n_in; (void)out_size;

    int PB = (E + CH - 1) / CH;

    (void)hipMemsetAsync(bhist, 0, 512 * 4, stream);
    hist_kernel     <<<512, 256, 0, stream>>>(dst, bhist, E, K);
    bscan_kernel    <<<1, 512, 0, stream>>>(bhist, bbase, bcur, rp, K, E, N);
    partition_kernel<<<PB, 256, 0, stream>>>(src, dst, bcur, pairs, E);
    build_kernel    <<<K, 256, 0, stream>>>(pairs, bbase, rp, dis, col, N);

    wt_kernel<<<2 * FD, FD, 0, stream>>>(W1, w1t, W2, w2t);

    dim3 aggBlk(64, 4);
    int aggGrid = (N + 3) / 4;
    int gemmGrid = (N + 127) / 128;

    gemm_mfma_f32 <<<gemmGrid, 256, 0, stream>>>(x, w1t, dis, hbuf, N);
    agg_kernel<<<aggGrid, aggBlk, 0, stream>>>((const unsigned*)hbuf, dis, rp, col,
                                               (const float4*)b1, z1, N, 1);
    gemm_mfma_bf16<<<gemmGrid, 256, 0, stream>>>(z1, w2t, dis, hbuf, N);
    agg_kernel<<<aggGrid, aggBlk, 0, stream>>>((const unsigned*)hbuf, dis, rp, col,
                                               (const float4*)b2, d_out, N, 0);
}

// Round 10
// 259.846 us; speedup vs baseline: 1.1996x; 1.1996x over previous
//
#include <hip/hip_runtime.h>

#define FD 128      // feature dim (both layers)
#define BSH 7       // log2(nodes per bucket) = 128 nodes/bucket
#define BPAD 16     // cursor padding (ints) -> one per 64B line
#define CH 4096     // edges per partition block
#define CHT 16      // edges per thread (CH / 256)
// packed pair: (local_dst << 17) | src   -- requires N <= 131072

typedef __attribute__((ext_vector_type(8))) short bf16x8;
typedef __attribute__((ext_vector_type(4))) float f32x4;

__device__ inline unsigned bfr(float f) {   // fp32 -> bf16 bits, round-nearest-even
    unsigned u = __float_as_uint(f);
    return (u + 0x7FFF + ((u >> 16) & 1)) >> 16;
}
__device__ inline float uplo(unsigned p) { return __uint_as_float(p << 16); }
__device__ inline float uphi(unsigned p) { return __uint_as_float(p & 0xFFFF0000u); }

// ---------------- CSR build ----------------

__global__ __launch_bounds__(256) void hist_kernel(
        const int* __restrict__ dst, int* __restrict__ bhist, int E, int K) {
    __shared__ int lh[512];
    for (int i = threadIdx.x; i < K; i += 256) lh[i] = 0;
    __syncthreads();
    for (int e = blockIdx.x * 256 + threadIdx.x; e < E; e += gridDim.x * 256)
        atomicAdd(&lh[dst[e] >> BSH], 1);
    __syncthreads();
    for (int i = threadIdx.x; i < K; i += 256)
        if (lh[i]) atomicAdd(&bhist[i], lh[i]);
}

__global__ __launch_bounds__(512) void bscan_kernel(
        const int* __restrict__ bhist, int* __restrict__ bbase, int* __restrict__ bcur,
        int* __restrict__ rp, int K, int E, int N) {
    __shared__ int sm[512];
    int t = threadIdx.x;
    int v = (t < K) ? bhist[t] : 0;
    sm[t] = v;
    __syncthreads();
    for (int off = 1; off < 512; off <<= 1) {
        int add = (t >= off) ? sm[t - off] : 0;
        __syncthreads();
        sm[t] += add;
        __syncthreads();
    }
    if (t < K) { bbase[t] = sm[t] - v; bcur[t * BPAD] = sm[t] - v; }
    if (t == 0) { bbase[K] = E; rp[N] = E; }
}

// Block-local multi-split partition (R6: ~1-2 writebacks per pairs-line,
// independent of block->XCD placement).
__global__ __launch_bounds__(256) void partition_kernel(
        const int* __restrict__ src, const int* __restrict__ dst,
        int* __restrict__ bcur, int* __restrict__ pairs, int E) {
    __shared__ int   lcnt[512];
    __shared__ int   lstart[512];
    __shared__ int   ldelta[512];
    __shared__ int   sm[256];
    __shared__ int   staged[CH];
    __shared__ short binof[CH];
    int t = threadIdx.x;
    int base = blockIdx.x * CH;
    int n = min(CH, E - base);

    lcnt[t] = 0; lcnt[t + 256] = 0;
    __syncthreads();

    int pk[CHT]; int bn[CHT];
    #pragma unroll
    for (int j = 0; j < CHT; ++j) {
        int i = t + j * 256;
        bn[j] = -1;
        if (i < n) {
            int d = dst[base + i];
            int s = src[base + i];
            bn[j] = d >> BSH;
            pk[j] = ((d & ((1 << BSH) - 1)) << 17) | s;
            atomicAdd(&lcnt[bn[j]], 1);
        }
    }
    __syncthreads();

    int c0 = lcnt[2 * t], c1 = lcnt[2 * t + 1];
    int s2 = c0 + c1;
    sm[t] = s2;
    __syncthreads();
    for (int off = 1; off < 256; off <<= 1) {
        int add = (t >= off) ? sm[t - off] : 0;
        __syncthreads();
        sm[t] += add;
        __syncthreads();
    }
    int ex = sm[t] - s2;
    lstart[2 * t] = ex;     lstart[2 * t + 1] = ex + c0;
    lcnt[2 * t]   = ex;     lcnt[2 * t + 1]   = ex + c0;
    __syncthreads();

    #pragma unroll
    for (int j = 0; j < CHT; ++j) {
        if (bn[j] >= 0) {
            int pos = atomicAdd(&lcnt[bn[j]], 1);
            staged[pos] = pk[j];
            binof[pos] = (short)bn[j];
        }
    }
    __syncthreads();

    #pragma unroll
    for (int k = 0; k < 2; ++k) {
        int b = 2 * t + k;
        int cnt = lcnt[b] - lstart[b];
        if (cnt > 0) {
            int g = atomicAdd(&bcur[b * BPAD], cnt);
            ldelta[b] = g - lstart[b];
        }
    }
    __syncthreads();

    for (int i = t; i < n; i += 256)
        pairs[ldelta[binof[i]] + i] = staged[i];
}

__global__ __launch_bounds__(256) void build_kernel(
        const int* __restrict__ pairs, const int* __restrict__ bbase,
        int* __restrict__ rp, float* __restrict__ dis, int* __restrict__ col, int N) {
    __shared__ int lcnt[1 << BSH];
    __shared__ int lsum[1 << BSH];
    __shared__ int lbase[1 << BSH];
    int b = blockIdx.x;
    int t = threadIdx.x;
    int nbase = b << BSH;
    int nn = min(1 << BSH, N - nbase);
    int beg = bbase[b], end = bbase[b + 1];
    if (t < 128) lcnt[t] = 0;
    __syncthreads();
    for (int e = beg + t; e < end; e += 256)
        atomicAdd(&lcnt[pairs[e] >> 17], 1);
    __syncthreads();
    if (t < 128) lsum[t] = lcnt[t];
    __syncthreads();
    for (int off = 1; off < 128; off <<= 1) {
        int add = (t < 128 && t >= off) ? lsum[t - off] : 0;
        __syncthreads();
        if (t < 128) lsum[t] += add;
        __syncthreads();
    }
    if (t < 128) {
        int excl = beg + lsum[t] - lcnt[t];
        lbase[t] = excl;
        if (t < nn) {
            rp[nbase + t] = excl;
            dis[nbase + t] = rsqrtf((float)(lcnt[t] + 1));  // deg incl. self-loop
        }
    }
    __syncthreads();
    if (t < 128) lcnt[t] = lbase[t];
    __syncthreads();
    for (int e = beg + t; e < end; e += 256) {
        int p = pairs[e];
        int pos = atomicAdd(&lcnt[p >> 17], 1);
        col[pos] = p & 0x1FFFF;
    }
}

// ---------------- precision prep ----------------

// W[k][n] fp32 -> WT[n][k] bf16, both weights in one launch (gridDim.x = 2*FD)
__global__ void wt_kernel(const float* __restrict__ W1, unsigned short* __restrict__ W1T,
                          const float* __restrict__ W2, unsigned short* __restrict__ W2T) {
    int k = blockIdx.x & (FD - 1);
    int n = threadIdx.x;
    if (blockIdx.x < FD) W1T[n * FD + k] = (unsigned short)bfr(W1[k * FD + n]);
    else                 W2T[n * FD + k] = (unsigned short)bfr(W2[k * FD + n]);
}

// ---------------- MFMA bf16 GEMM: C = bf16( dis[row] * (A @ W) ) ----------------
// WT: [128 x 128] bf16, WT[n][k]. Block: 128 rows, full K=N=128 in LDS.
// 4 waves, 32 rows each. Mappings (guide-verified): A[m=lane&15][k=quad*8+j],
// B[k=quad*8+j][n=lane&15], C/D row=quad*4+reg, col=lane&15.
// A32 variant: A is fp32, converted to bf16 during staging (fuses cvt pass).

#define APAD 8
#define ASTR (FD + APAD)

template <bool A32>
__device__ void gemm_body(const void* __restrict__ Ap,
                          const unsigned short* __restrict__ WT,
                          const float* __restrict__ dis,
                          unsigned short* __restrict__ C, int M) {
    __shared__ unsigned short As[128 * ASTR];
    __shared__ unsigned short Bs[128 * ASTR];
    int tid = threadIdx.x;
    int lane = tid & 63;
    int wave = tid >> 6;
    int quad = lane >> 4;
    int l16 = lane & 15;
    int rowBase = blockIdx.x * 128;

    #pragma unroll
    for (int p = 0; p < 8; ++p) {
        int r = p * 16 + (tid >> 4);
        int cq = (tid & 15) * 8;
        int gr = rowBase + r;
        uint4 v = make_uint4(0u, 0u, 0u, 0u);
        if (A32) {
            if (gr < M) {
                const float* a = (const float*)Ap + (size_t)gr * FD + cq;
                float4 f0 = *(const float4*)a;
                float4 f1 = *(const float4*)(a + 4);
                v.x = bfr(f0.x) | (bfr(f0.y) << 16);
                v.y = bfr(f0.z) | (bfr(f0.w) << 16);
                v.z = bfr(f1.x) | (bfr(f1.y) << 16);
                v.w = bfr(f1.z) | (bfr(f1.w) << 16);
            }
        } else {
            if (gr < M) v = *(const uint4*)((const unsigned short*)Ap + (size_t)gr * FD + cq);
        }
        *(uint4*)&As[r * ASTR + cq] = v;
        *(uint4*)&Bs[r * ASTR + cq] = *(const uint4*)&WT[(size_t)r * FD + cq];
    }
    __syncthreads();

    int m0 = wave * 32;
    f32x4 acc[2][8] = {};
    #pragma unroll
    for (int kt = 0; kt < 4; ++kt) {
        int ko = kt * 32 + quad * 8;
        bf16x8 a0 = *(bf16x8*)&As[(m0 + l16) * ASTR + ko];
        bf16x8 a1 = *(bf16x8*)&As[(m0 + 16 + l16) * ASTR + ko];
        #pragma unroll
        for (int n = 0; n < 8; ++n) {
            bf16x8 b = *(bf16x8*)&Bs[(n * 16 + l16) * ASTR + ko];
            acc[0][n] = __builtin_amdgcn_mfma_f32_16x16x32_bf16(a0, b, acc[0][n], 0, 0, 0);
            acc[1][n] = __builtin_amdgcn_mfma_f32_16x16x32_bf16(a1, b, acc[1][n], 0, 0, 0);
        }
    }

    #pragma unroll
    for (int ms = 0; ms < 2; ++ms) {
        #pragma unroll
        for (int r = 0; r < 4; ++r) {
            int grow = rowBase + m0 + ms * 16 + quad * 4 + r;
            if (grow < M) {
                float dv = dis[grow];
                #pragma unroll
                for (int n = 0; n < 8; ++n) {
                    C[(size_t)grow * FD + n * 16 + l16] =
                        (unsigned short)bfr(dv * acc[ms][n][r]);
                }
            }
        }
    }
}

__global__ __launch_bounds__(256) void gemm_mfma_f32(
        const float* __restrict__ A, const unsigned short* __restrict__ WT,
        const float* __restrict__ dis, unsigned short* __restrict__ C, int M) {
    gemm_body<true>(A, WT, dis, C, M);
}

__global__ __launch_bounds__(256) void gemm_mfma_bf16(
        const unsigned short* __restrict__ A, const unsigned short* __restrict__ WT,
        const float* __restrict__ dis, unsigned short* __restrict__ C, int M) {
    gemm_body<false>(A, WT, dis, C, M);
}

// ---------------- CSR aggregation + bias + ReLU ----------------
// h' rows pre-scaled by dis, stored bf16 (2 per uint). One node per wave;
// lane t holds features [2t, 2t+1]. Plain cached loads (NO nontemporal: h is
// ~32x-reused, nt evict-first killed the L2 hit rate in R9). 16 edges in
// flight per wave (R10: test outstanding-capacity vs R7's 8-deep).
// out[v] = relu( dis[v] * ( h'[v] + sum_u h'[u] ) + b )
// obf=1: write packed bf16 (z1, feeds gemm2); obf=0: write fp32 (final out).

__global__ __launch_bounds__(256) void agg_kernel(
        const unsigned* __restrict__ h, const float* __restrict__ dis,
        const int* __restrict__ rp, const int* __restrict__ col,
        const float2* __restrict__ bias, void* __restrict__ out, int N, int obf) {
    int v = blockIdx.x * 4 + threadIdx.y;          // blockDim = (64, 4): wave per node
    v = __builtin_amdgcn_readfirstlane(v);         // wave-uniform -> scalar rp/col loads
    if (v >= N) return;
    int t = threadIdx.x;                           // 0..63
    float dv = dis[v];
    size_t vb = (size_t)v * 64 + t;
    unsigned hp = h[vb];                           // self term h'[v]
    float2 acc;
    acc.x = uplo(hp); acc.y = uphi(hp);
    int e = rp[v];
    int end = rp[v + 1];

    for (; e + 16 <= end; e += 16) {
        int u[16];
        #pragma unroll
        for (int j = 0; j < 16; ++j) u[j] = col[e + j];   // wave-uniform scalar loads
        unsigned p[16];
        #pragma unroll
        for (int j = 0; j < 16; ++j) p[j] = h[(size_t)u[j] * 64 + t];
        #pragma unroll
        for (int j = 0; j < 16; ++j) {
            acc.x += uplo(p[j]); acc.y += uphi(p[j]);
        }
    }
    for (; e + 4 <= end; e += 4) {
        int u0 = col[e], u1 = col[e + 1], u2 = col[e + 2], u3 = col[e + 3];
        unsigned p0 = h[(size_t)u0 * 64 + t];
        unsigned p1 = h[(size_t)u1 * 64 + t];
        unsigned p2 = h[(size_t)u2 * 64 + t];
        unsigned p3 = h[(size_t)u3 * 64 + t];
        acc.x += uplo(p0); acc.y += uphi(p0);
        acc.x += uplo(p1); acc.y += uphi(p1);
        acc.x += uplo(p2); acc.y += uphi(p2);
        acc.x += uplo(p3); acc.y += uphi(p3);
    }
    for (; e < end; ++e) {
        unsigned p = h[(size_t)col[e] * 64 + t];
        acc.x += uplo(p); acc.y += uphi(p);
    }

    float2 bb = bias[t];
    float2 r;
    r.x = fmaxf(fmaf(dv, acc.x, bb.x), 0.0f);
    r.y = fmaxf(fmaf(dv, acc.y, bb.y), 0.0f);
    if (obf) {
        ((unsigned*)out)[vb] = bfr(r.x) | (bfr(r.y) << 16);
    } else {
        ((float2*)out)[vb] = r;
    }
}

// ---------------- launch ----------------

extern "C" void kernel_launch(void* const* d_in, const int* in_sizes, int n_in,
                              void* d_out, int out_size, void* d_ws, size_t ws_size,
                              hipStream_t stream) {
    const float* x  = (const float*)d_in[0];
    const int*   ei = (const int*)d_in[1];   // [2, E] int32
    const float* W1 = (const float*)d_in[2];
    const float* b1 = (const float*)d_in[3];
    const float* W2 = (const float*)d_in[4];
    const float* b2 = (const float*)d_in[5];

    int N = in_sizes[0] / FD;
    int E = in_sizes[1] / 2;
    const int* src = ei;
    const int* dst = ei + E;
    int K = (N + (1 << BSH) - 1) >> BSH;     // buckets (<= 512 assumed)

    char* base = (char*)d_ws;
    size_t off = 0;
    auto align256 = [](size_t v) { return (v + 255) & ~(size_t)255; };
    int*            rp    = (int*)(base + off);            off += align256((size_t)(N + 1) * 4);
    float*          dis   = (float*)(base + off);          off += align256((size_t)N * 4);
    int*            bhist = (int*)(base + off);            off += align256(512 * 4);
    int*            bbase = (int*)(base + off);            off += align256(513 * 4);
    int*            bcur  = (int*)(base + off);            off += align256((size_t)K * BPAD * 4);
    unsigned short* w1t   = (unsigned short*)(base + off); off += align256((size_t)FD * FD * 2);
    unsigned short* w2t   = (unsigned short*)(base + off); off += align256((size_t)FD * FD * 2);
    int*            col   = (int*)(base + off);            off += align256((size_t)E * 4);
    unsigned short* hbuf  = (unsigned short*)(base + off); off += align256((size_t)N * FD * 2);
    unsigned short* z1    = (unsigned short*)(base + off); off += align256((size_t)N * FD * 2);
    int*            pairs = (int*)(base + off);            off += align256((size_t)E * 4);
    (void)ws_size; (void)n_in; (void)out_size;

    int PB = (E + CH - 1) / CH;

    (void)hipMemsetAsync(bhist, 0, 512 * 4, stream);
    hist_kernel     <<<512, 256, 0, stream>>>(dst, bhist, E, K);
    bscan_kernel    <<<1, 512, 0, stream>>>(bhist, bbase, bcur, rp, K, E, N);
    partition_kernel<<<PB, 256, 0, stream>>>(src, dst, bcur, pairs, E);
    build_kernel    <<<K, 256, 0, stream>>>(pairs, bbase, rp, dis, col, N);

    wt_kernel<<<2 * FD, FD, 0, stream>>>(W1, w1t, W2, w2t);

    dim3 aggBlk(64, 4);
    int aggGrid = (N + 3) / 4;
    int gemmGrid = (N + 127) / 128;

    gemm_mfma_f32 <<<gemmGrid, 256, 0, stream>>>(x, w1t, dis, hbuf, N);
    agg_kernel<<<aggGrid, aggBlk, 0, stream>>>((const unsigned*)hbuf, dis, rp, col,
                                               (const float2*)b1, z1, N, 1);
    gemm_mfma_bf16<<<gemmGrid, 256, 0, stream>>>(z1, w2t, dis, hbuf, N);
    agg_kernel<<<aggGrid, aggBlk, 0, stream>>>((const unsigned*)hbuf, dis, rp, col,
                                               (const float2*)b2, d_out, N, 0);
}